// Round 5
// baseline (660.875 us; speedup 1.0000x reference)
//
#include <hip/hip_runtime.h>

#define NB 16    // N*G
#define CD 64    // C == Cv
#define HD 2048  // H
#define LOG2E 1.44269504088896340736f
#define PSTRIDE 4160   // per-partial floats: 64*64 acc + 64 reduce

typedef unsigned short u16;
typedef __attribute__((ext_vector_type(8))) short s16x8;  // 8 bf16 (4 VGPRs)
typedef __attribute__((ext_vector_type(4))) float f32x4;  // 16x16 MFMA C/D

extern "C" __device__ float __ocml_native_exp2_f32(float);
__device__ __forceinline__ float fexp2(float x){ return __ocml_native_exp2_f32(x); }

// ---- RNE split (prep kernels only) ----
__device__ __forceinline__ u16 f2bf(float x){
    unsigned u = __float_as_uint(x);
    u += 0x7FFFu + ((u >> 16) & 1u);
    return (u16)(u >> 16);
}
__device__ __forceinline__ float bf2f(u16 h){ return __uint_as_float(((unsigned)h) << 16); }
__device__ __forceinline__ void split2(float x, u16& h, u16& l){
    h = f2bf(x); l = f2bf(x - bf2f(h));
}
// ---- trunc split (hot path) ----
__device__ __forceinline__ float hi_f(float x){ return __uint_as_float(__float_as_uint(x) & 0xffff0000u); }
__device__ __forceinline__ unsigned pk2(float a, float b){
    return __builtin_amdgcn_perm(__float_as_uint(b), __float_as_uint(a), 0x07060302);
}

union Frag { uint4 q; s16x8 s; };
__device__ __forceinline__ s16x8 ld8(const u16* p){ Frag f; f.q = *(const uint4*)p; return f.s; }
__device__ __forceinline__ f32x4 mfma16(s16x8 a, s16x8 b, f32x4 c){
    return __builtin_amdgcn_mfma_f32_16x16x32_bf16(a, b, c, 0, 0, 0);
}
__device__ __forceinline__ f32x4 mm3(s16x8 ah, s16x8 al, s16x8 bh, s16x8 bl, f32x4 c){
    c = mfma16(ah, bh, c);
    c = mfma16(ah, bl, c);
    c = mfma16(al, bh, c);
    return c;
}
__device__ __forceinline__ f32x4 z4(){ f32x4 v = {0.f,0.f,0.f,0.f}; return v; }

// XCD-aware remap for 1024 blocks: (bg, tile[0..32), half[0..2)); same bg clusters per XCD,
// the two halves of a tile are adjacent slots (share resident-operand L2 lines).
__device__ __forceinline__ void remap(int lin, int& bg, int& tile, int& half){
    int xcd = lin & 7, slot = lin >> 3;     // slot 0..127
    bg   = xcd + 8*(slot >> 6);             // 2 bgs per XCD
    int r2 = slot & 63;
    tile = r2 >> 1;
    half = r2 & 1;
}

// ---------------- prep kernels ----------------

// q: fp32 [c][h] -> qN hi/lo (natural) + qT hi/lo (transposed [h][c])
__global__ void k_prep_q(const float* __restrict__ src,
                         u16* __restrict__ nh, u16* __restrict__ nl,
                         u16* __restrict__ th, u16* __restrict__ tl)
{
    int bg = blockIdx.y, h0 = blockIdx.x*128, tid = threadIdx.x;
    __shared__ float ft[CD][132];
    #pragma unroll
    for (int k=0;k<8;k++){
        int flat = tid + 256*k;
        int c = flat >> 5, p = (flat & 31)*4;
        size_t gidx = ((size_t)bg*CD + c)*HD + h0 + p;
        float4 v = *(const float4*)(src + gidx);
        *(float4*)&ft[c][p] = v;
        ushort4 h, l;
        split2(v.x, h.x, l.x); split2(v.y, h.y, l.y);
        split2(v.z, h.z, l.z); split2(v.w, h.w, l.w);
        *(ushort4*)(nh + gidx) = h;
        *(ushort4*)(nl + gidx) = l;
    }
    __syncthreads();
    int hl = tid >> 1, c0 = (tid & 1)*32;
    union { u16 u[32]; uint4 q[4]; } oh, ol;
    #pragma unroll
    for (int m=0;m<32;m++){
        float x = ft[c0+m][hl];
        u16 hh; split2(x, hh, ol.u[m]); oh.u[m] = hh;
    }
    size_t base = ((size_t)bg*HD + h0 + hl)*CD + c0;
    #pragma unroll
    for (int t=0;t<4;t++){
        *((uint4*)(th + base) + t) = oh.q[t];
        *((uint4*)(tl + base) + t) = ol.q[t];
    }
}

// zeta: transpose only
__global__ void k_prep_z(const float* __restrict__ src,
                         u16* __restrict__ th, u16* __restrict__ tl)
{
    int bg = blockIdx.y, h0 = blockIdx.x*128, tid = threadIdx.x;
    __shared__ float ft[CD][132];
    #pragma unroll
    for (int k=0;k<8;k++){
        int flat = tid + 256*k;
        int c = flat >> 5, p = (flat & 31)*4;
        *(float4*)&ft[c][p] = *(const float4*)(src + ((size_t)bg*CD + c)*HD + h0 + p);
    }
    __syncthreads();
    int hl = tid >> 1, c0 = (tid & 1)*32;
    union { u16 u[32]; uint4 q[4]; } oh, ol;
    #pragma unroll
    for (int m=0;m<32;m++){
        float x = ft[c0+m][hl];
        u16 hh; split2(x, hh, ol.u[m]); oh.u[m] = hh;
    }
    size_t base = ((size_t)bg*HD + h0 + hl)*CD + c0;
    #pragma unroll
    for (int t=0;t<4;t++){
        *((uint4*)(th + base) + t) = oh.q[t];
        *((uint4*)(tl + base) + t) = ol.q[t];
    }
}

// mu: convert natural hi/lo + bias2[j] = 0.5*beta*log2e*sum_c mu^2
__global__ void k_prep_mu(const float* __restrict__ mu, const float* __restrict__ beta,
                          u16* __restrict__ nh, u16* __restrict__ nl,
                          float* __restrict__ bias2)
{
    int bg = blockIdx.y;
    int j  = blockIdx.x*256 + threadIdx.x;
    float s = 0.f;
    #pragma unroll 8
    for (int c=0;c<CD;c++){
        size_t idx = ((size_t)bg*CD + c)*HD + j;
        float v = mu[idx];
        u16 h, l; split2(v, h, l);
        nh[idx] = h; nl[idx] = l;
        s = fmaf(v, v, s);
    }
    bias2[(size_t)bg*HD + j] = 0.5f * beta[0] * LOG2E * s;
}

// ---------------- main MFMA kernels (16x16x32, split-K halves) ----------------
// logit2_ij = a2*S_ij + bias2_j  (z2 terms cancel; row const drops in softmax)

// partial r: rp[half][bg][i] = sum_{j in half} exp2(...). Block: 64 i resident, sweeps 1024 j.
__global__ __launch_bounds__(256,3) void k_rowsum(
    const u16* __restrict__ qTh, const u16* __restrict__ qTl,
    const u16* __restrict__ zTh, const u16* __restrict__ zTl,
    const float* __restrict__ bias2, const float* __restrict__ alpha,
    float* __restrict__ rp)
{
    int bg, tile, half; remap(blockIdx.x, bg, tile, half);
    const int i0 = tile*64, jbase = half*(HD/2);
    const int tid = threadIdx.x, wave = tid>>6, lane = tid&63, ln = lane&15, quad = lane>>4;
    const float a2 = alpha[0]*LOG2E;
    __shared__ float rpart[4][64];

    s16x8 Ah[4][2], Al[4][2];     // resident q^T rows i0..i0+63
    #pragma unroll
    for (int mt=0;mt<4;mt++)
        #pragma unroll
        for (int ks=0;ks<2;ks++){
            size_t off = ((size_t)bg*HD + i0 + mt*16 + ln)*CD + ks*32 + quad*8;
            Ah[mt][ks] = ld8(qTh + off);
            Al[mt][ks] = ld8(qTl + off);
        }
    float racc[16];
    #pragma unroll
    for (int k=0;k<16;k++) racc[k] = 0.f;
    const float* bb = bias2 + (size_t)bg*HD;

    for (int s=0;s<8;s++){
        const int jw = jbase + s*128 + wave*32;
        f32x4 acc[4][2];
        #pragma unroll
        for (int mt=0;mt<4;mt++){ acc[mt][0]=z4(); acc[mt][1]=z4(); }
        #pragma unroll
        for (int ks=0;ks<2;ks++){
            s16x8 Bh[2], Bl[2];
            #pragma unroll
            for (int nt=0;nt<2;nt++){
                size_t off = ((size_t)bg*HD + jw + nt*16 + ln)*CD + ks*32 + quad*8;
                Bh[nt] = ld8(zTh + off);
                Bl[nt] = ld8(zTl + off);
            }
            #pragma unroll
            for (int mt=0;mt<4;mt++)
                #pragma unroll
                for (int nt=0;nt<2;nt++)
                    acc[mt][nt] = mm3(Ah[mt][ks], Al[mt][ks], Bh[nt], Bl[nt], acc[mt][nt]);
        }
        float bj[2];
        #pragma unroll
        for (int nt=0;nt<2;nt++) bj[nt] = bb[jw + nt*16 + ln];
        #pragma unroll
        for (int mt=0;mt<4;mt++)
            #pragma unroll
            for (int nt=0;nt<2;nt++)
                #pragma unroll
                for (int rx=0;rx<4;rx++)
                    racc[mt*4+rx] += fexp2(fmaf(a2, acc[mt][nt][rx], bj[nt]));
    }
    #pragma unroll
    for (int k=0;k<16;k++){
        float v = racc[k];
        v += __shfl_xor(v,1); v += __shfl_xor(v,2);
        v += __shfl_xor(v,4); v += __shfl_xor(v,8);
        racc[k] = v;
    }
    if (ln == 0){
        #pragma unroll
        for (int mt=0;mt<4;mt++)
            #pragma unroll
            for (int rx=0;rx<4;rx++)
                rpart[wave][mt*16 + quad*4 + rx] = racc[mt*4+rx];
    }
    __syncthreads();
    if (tid < 64)
        rp[(size_t)half*NB*HD + (size_t)bg*HD + i0 + tid]
            = rpart[0][tid]+rpart[1][tid]+rpart[2][tid]+rpart[3][tid];
}

// zeta-update partials. Block: 64 j resident; sweeps 1024 i.
// writes upart[kb]: num[c][jl] (64x64 fp32) + den[jl] (64)
__global__ __launch_bounds__(256,4) void k_update(
    const u16* __restrict__ qTh, const u16* __restrict__ qTl,
    const u16* __restrict__ zTh, const u16* __restrict__ zTl,
    const u16* __restrict__ qNh, const u16* __restrict__ qNl,
    const float* __restrict__ bias2, const float* __restrict__ alpha,
    const float* __restrict__ rp, float* __restrict__ upart)
{
    int bg, tile, half; remap(blockIdx.x, bg, tile, half);
    const int j0 = tile*64, ibase = half*(HD/2);
    const int tid = threadIdx.x, wave = tid>>6, lane = tid&63, ln = lane&15, quad = lane>>4;
    const int cm = (wave&1)*32, jn = (wave>>1)*32;
    const float a2 = alpha[0]*LOG2E;
    __shared__ u16 wlh[64*128], wll[64*128];   // w^T tile [j][i], 16B-block XOR swizzle
    __shared__ float denl[4][64];
    const float* rp0 = rp + (size_t)bg*HD;
    const float* rp1 = rp + (size_t)NB*HD + (size_t)bg*HD;

    s16x8 Bh[4][2], Bl[4][2];     // resident z^T rows j0..j0+63
    #pragma unroll
    for (int nt=0;nt<4;nt++)
        #pragma unroll
        for (int ks=0;ks<2;ks++){
            size_t off = ((size_t)bg*HD + j0 + nt*16 + ln)*CD + ks*32 + quad*8;
            Bh[nt][ks] = ld8(zTh + off);
            Bl[nt][ks] = ld8(zTl + off);
        }
    float bj[4];
    #pragma unroll
    for (int nt=0;nt<4;nt++) bj[nt] = bias2[(size_t)bg*HD + j0 + nt*16 + ln];

    f32x4 acc2[2][2] = {{z4(),z4()},{z4(),z4()}};
    float den[4] = {0.f,0.f,0.f,0.f};

    for (int s=0;s<8;s++){
        const int is = ibase + s*128;
        // ---- phase A: S tile (m = i: wave*32 + 2 mt; n = own j: 4 nt) ----
        f32x4 acc1[2][4];
        #pragma unroll
        for (int mt=0;mt<2;mt++)
            #pragma unroll
            for (int nt=0;nt<4;nt++) acc1[mt][nt] = z4();
        #pragma unroll
        for (int ks=0;ks<2;ks++){
            s16x8 Ah[2], Al[2];
            #pragma unroll
            for (int mt=0;mt<2;mt++){
                size_t off = ((size_t)bg*HD + is + wave*32 + mt*16 + ln)*CD + ks*32 + quad*8;
                Ah[mt] = ld8(qTh + off);
                Al[mt] = ld8(qTl + off);
            }
            #pragma unroll
            for (int mt=0;mt<2;mt++)
                #pragma unroll
                for (int nt=0;nt<4;nt++)
                    acc1[mt][nt] = mm3(Ah[mt], Al[mt], Bh[nt][ks], Bl[nt][ks], acc1[mt][nt]);
        }
        float ri[8];
        #pragma unroll
        for (int mt=0;mt<2;mt++){
            int rb = is + wave*32 + mt*16 + quad*4;
            float4 r0 = *(const float4*)(rp0 + rb);
            float4 r1 = *(const float4*)(rp1 + rb);
            ri[mt*4+0] = __builtin_amdgcn_rcpf(r0.x + r1.x);
            ri[mt*4+1] = __builtin_amdgcn_rcpf(r0.y + r1.y);
            ri[mt*4+2] = __builtin_amdgcn_rcpf(r0.z + r1.z);
            ri[mt*4+3] = __builtin_amdgcn_rcpf(r0.w + r1.w);
        }
        __syncthreads();   // prev step's phase-B reads of wl done
        #pragma unroll
        for (int mt=0;mt<2;mt++)
            #pragma unroll
            for (int nt=0;nt<4;nt++){
                float w[4], lo[4];
                #pragma unroll
                for (int rx=0;rx<4;rx++){
                    w[rx] = fexp2(fmaf(a2, acc1[mt][nt][rx], bj[nt])) * ri[mt*4+rx];
                    lo[rx] = w[rx] - hi_f(w[rx]);
                }
                den[nt] += (w[0]+w[1]) + (w[2]+w[3]);
                int row = nt*16 + ln;                     // j-local
                int c4  = wave*32 + mt*16 + quad*4;       // i-local
                int off = (row<<7) + ((((c4>>3) ^ (row&15))<<3) | (c4&7));
                *(uint2*)&wlh[off] = make_uint2(pk2(w[0],w[1]),  pk2(w[2],w[3]));
                *(uint2*)&wll[off] = make_uint2(pk2(lo[0],lo[1]), pk2(lo[2],lo[3]));
            }
        __syncthreads();
        // ---- phase B: acc2[c][j] += qN.w  (m = c: cm+2mtN; n = j: jn+2nt2; k = i: 4 ks2) ----
        #pragma unroll
        for (int ks2=0;ks2<4;ks2++){
            s16x8 A2h[2], A2l[2], B2h[2], B2l[2];
            #pragma unroll
            for (int mtN=0;mtN<2;mtN++){
                size_t off = ((size_t)bg*CD + cm + mtN*16 + ln)*HD + is + ks2*32 + quad*8;
                A2h[mtN] = ld8(qNh + off);
                A2l[mtN] = ld8(qNl + off);
            }
            #pragma unroll
            for (int nt2=0;nt2<2;nt2++){
                int jl = jn + nt2*16 + ln;
                int ob = (jl<<7) + (((ks2*4 + quad) ^ (jl&15))<<3);
                B2h[nt2] = ld8(&wlh[ob]);
                B2l[nt2] = ld8(&wll[ob]);
            }
            #pragma unroll
            for (int mtN=0;mtN<2;mtN++)
                #pragma unroll
                for (int nt2=0;nt2<2;nt2++)
                    acc2[mtN][nt2] = mm3(A2h[mtN], A2l[mtN], B2h[nt2], B2l[nt2], acc2[mtN][nt2]);
        }
    }
    // den reduce: quads via shfl, waves via LDS
    #pragma unroll
    for (int nt=0;nt<4;nt++){
        float v = den[nt];
        v += __shfl_xor(v,16); v += __shfl_xor(v,32);
        if (quad == 0) denl[wave][nt*16 + ln] = v;
    }
    __syncthreads();
    const int kb = ((bg*32 + tile)<<1) + half;
    float* up = upart + (size_t)kb*PSTRIDE;
    #pragma unroll
    for (int mtN=0;mtN<2;mtN++)
        #pragma unroll
        for (int nt2=0;nt2<2;nt2++)
            #pragma unroll
            for (int rx=0;rx<4;rx++){
                int c  = cm + mtN*16 + quad*4 + rx;
                int jl = jn + nt2*16 + ln;
                up[c*64 + jl] = acc2[mtN][nt2][rx];
            }
    if (tid < 64)
        up[4096 + tid] = denl[0][tid]+denl[1][tid]+denl[2][tid]+denl[3][tid];
}

// combine zeta partials -> zT hi/lo (in place over zT; runs after all readers)
__global__ void k_zcomb(const float* __restrict__ upart,
                        u16* __restrict__ zTh, u16* __restrict__ zTl)
{
    const int tile = blockIdx.x, bg = blockIdx.y, tid = threadIdx.x;
    const int j0 = tile*64;
    const float* p0 = upart + (size_t)(((bg*32 + tile)<<1) + 0)*PSTRIDE;
    const float* p1 = upart + (size_t)(((bg*32 + tile)<<1) + 1)*PSTRIDE;
    int jl = tid >> 2, c0 = (tid & 3)*16;
    float dinv = __builtin_amdgcn_rcpf(p0[4096 + jl] + p1[4096 + jl]);
    #pragma unroll
    for (int q=0;q<4;q++){
        int c = c0 + q*4;
        float v[4], lo[4];
        #pragma unroll
        for (int rx=0;rx<4;rx++){
            v[rx] = (p0[(c+rx)*64 + jl] + p1[(c+rx)*64 + jl]) * dinv;
            lo[rx] = v[rx] - hi_f(v[rx]);
        }
        size_t off = ((size_t)bg*HD + j0 + jl)*CD + c;
        *(uint2*)(zTh + off) = make_uint2(pk2(v[0],v[1]),  pk2(v[2],v[3]));
        *(uint2*)(zTl + off) = make_uint2(pk2(lo[0],lo[1]), pk2(lo[2],lo[3]));
    }
}

// final partials. Block: 64 i resident; sweeps 1024 j.
// writes fpart[kb]: acc[c][il] (64x64 fp32) + rsum[il] (64)
__global__ __launch_bounds__(256,4) void k_final(
    const u16* __restrict__ qTh, const u16* __restrict__ qTl,
    const u16* __restrict__ zTh, const u16* __restrict__ zTl,
    const u16* __restrict__ muh, const u16* __restrict__ mul_,
    const float* __restrict__ bias2, const float* __restrict__ alpha,
    float* __restrict__ fpart)
{
    int bg, tile, half; remap(blockIdx.x, bg, tile, half);
    const int i0 = tile*64, jbase = half*(HD/2);
    const int tid = threadIdx.x, wave = tid>>6, lane = tid&63, ln = lane&15, quad = lane>>4;
    const int cm = (wave&1)*32, in_ = (wave>>1)*32;
    const float a2 = alpha[0]*LOG2E;
    __shared__ u16 elh[64*128], ell[64*128];   // e^T tile [i][j], swizzled
    __shared__ float rl[4][64];

    s16x8 Bh[4][2], Bl[4][2];     // resident q^T rows i0..i0+63 (n operand)
    #pragma unroll
    for (int nt=0;nt<4;nt++)
        #pragma unroll
        for (int ks=0;ks<2;ks++){
            size_t off = ((size_t)bg*HD + i0 + nt*16 + ln)*CD + ks*32 + quad*8;
            Bh[nt][ks] = ld8(qTh + off);
            Bl[nt][ks] = ld8(qTl + off);
        }
    f32x4 acc2[2][2] = {{z4(),z4()},{z4(),z4()}};
    float racc[4] = {0.f,0.f,0.f,0.f};

    for (int s=0;s<8;s++){
        const int js = jbase + s*128;
        // ---- phase A: S'[j][i] (m = j: wave*32 + 2 mt; n = i: 4 nt) ----
        f32x4 acc1[2][4];
        #pragma unroll
        for (int mt=0;mt<2;mt++)
            #pragma unroll
            for (int nt=0;nt<4;nt++) acc1[mt][nt] = z4();
        #pragma unroll
        for (int ks=0;ks<2;ks++){
            s16x8 Ah[2], Al[2];
            #pragma unroll
            for (int mt=0;mt<2;mt++){
                size_t off = ((size_t)bg*HD + js + wave*32 + mt*16 + ln)*CD + ks*32 + quad*8;
                Ah[mt] = ld8(zTh + off);
                Al[mt] = ld8(zTl + off);
            }
            #pragma unroll
            for (int mt=0;mt<2;mt++)
                #pragma unroll
                for (int nt=0;nt<4;nt++)
                    acc1[mt][nt] = mm3(Ah[mt], Al[mt], Bh[nt][ks], Bl[nt][ks], acc1[mt][nt]);
        }
        float bj8[8];
        #pragma unroll
        for (int mt=0;mt<2;mt++)
            #pragma unroll
            for (int rx=0;rx<4;rx++)
                bj8[mt*4+rx] = bias2[(size_t)bg*HD + js + wave*32 + mt*16 + quad*4 + rx];
        __syncthreads();
        #pragma unroll
        for (int mt=0;mt<2;mt++)
            #pragma unroll
            for (int nt=0;nt<4;nt++){
                float e[4], lo[4];
                #pragma unroll
                for (int rx=0;rx<4;rx++){
                    e[rx] = fexp2(fmaf(a2, acc1[mt][nt][rx], bj8[mt*4+rx]));
                    lo[rx] = e[rx] - hi_f(e[rx]);
                }
                racc[nt] += (e[0]+e[1]) + (e[2]+e[3]);
                int row = nt*16 + ln;                     // i-local
                int jj  = wave*32 + mt*16 + quad*4;       // j-local
                int off = (row<<7) + ((((jj>>3) ^ (row&15))<<3) | (jj&7));
                *(uint2*)&elh[off] = make_uint2(pk2(e[0],e[1]),  pk2(e[2],e[3]));
                *(uint2*)&ell[off] = make_uint2(pk2(lo[0],lo[1]), pk2(lo[2],lo[3]));
            }
        __syncthreads();
        // ---- phase B: acc2[c][i] += mu.e^T  (m = c: cm+2mtN; n = i: in_+2nt2; k = j: 4 ks2) ----
        #pragma unroll
        for (int ks2=0;ks2<4;ks2++){
            s16x8 A2h[2], A2l[2], B2h[2], B2l[2];
            #pragma unroll
            for (int mtN=0;mtN<2;mtN++){
                size_t off = ((size_t)bg*CD + cm + mtN*16 + ln)*HD + js + ks2*32 + quad*8;
                A2h[mtN] = ld8(muh + off);
                A2l[mtN] = ld8(mul_ + off);
            }
            #pragma unroll
            for (int nt2=0;nt2<2;nt2++){
                int il = in_ + nt2*16 + ln;
                int ob = (il<<7) + (((ks2*4 + quad) ^ (il&15))<<3);
                B2h[nt2] = ld8(&elh[ob]);
                B2l[nt2] = ld8(&ell[ob]);
            }
            #pragma unroll
            for (int mtN=0;mtN<2;mtN++)
                #pragma unroll
                for (int nt2=0;nt2<2;nt2++)
                    acc2[mtN][nt2] = mm3(A2h[mtN], A2l[mtN], B2h[nt2], B2l[nt2], acc2[mtN][nt2]);
        }
    }
    #pragma unroll
    for (int nt=0;nt<4;nt++){
        float v = racc[nt];
        v += __shfl_xor(v,16); v += __shfl_xor(v,32);
        if (quad == 0) rl[wave][nt*16 + ln] = v;
    }
    __syncthreads();
    const int kb = ((bg*32 + tile)<<1) + half;
    float* fp = fpart + (size_t)kb*PSTRIDE;
    #pragma unroll
    for (int mtN=0;mtN<2;mtN++)
        #pragma unroll
        for (int nt2=0;nt2<2;nt2++)
            #pragma unroll
            for (int rx=0;rx<4;rx++){
                int c  = cm + mtN*16 + quad*4 + rx;
                int il = in_ + nt2*16 + ln;
                fp[c*64 + il] = acc2[mtN][nt2][rx];
            }
    if (tid < 64)
        fp[4096 + tid] = rl[0][tid]+rl[1][tid]+rl[2][tid]+rl[3][tid];
}

// combine final partials -> out fp32 [c][i]
__global__ void k_ocomb(const float* __restrict__ fpart, float* __restrict__ out)
{
    const int tile = blockIdx.x, bg = blockIdx.y, tid = threadIdx.x;
    const int i0 = tile*64;
    const float* p0 = fpart + (size_t)(((bg*32 + tile)<<1) + 0)*PSTRIDE;
    const float* p1 = fpart + (size_t)(((bg*32 + tile)<<1) + 1)*PSTRIDE;
    int il = tid & 63, c0 = (tid >> 6)*16;
    float rinv = __builtin_amdgcn_rcpf(p0[4096 + il] + p1[4096 + il]);
    #pragma unroll
    for (int k=0;k<16;k++){
        int c = c0 + k;
        out[((size_t)bg*CD + c)*HD + i0 + il]
            = (p0[c*64 + il] + p1[c*64 + il]) * rinv;
    }
}

extern "C" void kernel_launch(void* const* d_in, const int* in_sizes, int n_in,
                              void* d_out, int out_size, void* d_ws, size_t ws_size,
                              hipStream_t stream)
{
    (void)in_sizes; (void)n_in; (void)out_size; (void)ws_size;
    const float* q     = (const float*)d_in[0];
    const float* zeta  = (const float*)d_in[1];
    const float* alpha = (const float*)d_in[2];
    const float* mu    = (const float*)d_in[3];
    const float* beta  = (const float*)d_in[4];
    float* out = (float*)d_out;

    const size_t SZ = (size_t)NB*HD*CD;
    u16* qTh = (u16*)d_ws;
    u16* qTl = qTh + 1*SZ;
    u16* zTh = qTh + 2*SZ;
    u16* zTl = qTh + 3*SZ;
    u16* qNh = qTh + 4*SZ;
    u16* qNl = qTh + 5*SZ;
    u16* muh = qTh + 6*SZ;
    u16* mul_= qTh + 7*SZ;
    float* bias2 = (float*)(qTh + 8*SZ);
    float* rp    = bias2 + (size_t)NB*HD;          // 2 x NB*HD
    float* part  = rp + (size_t)2*NB*HD;           // 1024 x PSTRIDE (shared by upart/fpart)

    dim3 blk(256,1,1);
    k_prep_q <<<dim3(HD/128, NB), blk, 0, stream>>>(q, qNh, qNl, qTh, qTl);
    k_prep_z <<<dim3(HD/128, NB), blk, 0, stream>>>(zeta, zTh, zTl);
    k_prep_mu<<<dim3(HD/256, NB), blk, 0, stream>>>(mu, beta, muh, mul_, bias2);

    k_rowsum<<<dim3(1024), blk, 0, stream>>>(qTh,qTl,zTh,zTl,bias2,alpha,rp);
    k_update<<<dim3(1024), blk, 0, stream>>>(qTh,qTl,zTh,zTl,qNh,qNl,bias2,alpha,rp,part);
    k_zcomb <<<dim3(32,NB), blk, 0, stream>>>(part, zTh, zTl);

    k_rowsum<<<dim3(1024), blk, 0, stream>>>(qTh,qTl,zTh,zTl,bias2,alpha,rp);
    k_update<<<dim3(1024), blk, 0, stream>>>(qTh,qTl,zTh,zTl,qNh,qNl,bias2,alpha,rp,part);
    k_zcomb <<<dim3(32,NB), blk, 0, stream>>>(part, zTh, zTl);

    k_final <<<dim3(1024), blk, 0, stream>>>(qTh,qTl,zTh,zTl,muh,mul_,bias2,alpha,part);
    k_ocomb <<<dim3(32,NB), blk, 0, stream>>>(part, out);
}